// Round 6
// baseline (240.873 us; speedup 1.0000x reference)
//
#include <hip/hip_runtime.h>
#include <math.h>

// Hungarian matcher cost matrix:
//   C[n,t] = 5*L1(xyxy) + 2*(focal@label[t]) - 2*GIoU + 9999*inner
// N = 14400, T = 1024, C = 91. Output [N,T] f32 (59 MB).
//
// R6 = R5 with the nontemporal-store type fixed (needs a native clang
// vector, not HIP_vector_type). Design:
//   k1: focal table precomputed TRANSPOSED tableT[91][14400] in d_ws
//   k2: lane<->ROW mapping; per column t all target data is wave-uniform
//       (LDS broadcast, no gather); class cost is a coalesced global read
//       tableT[lab*N+n]; stores are per-lane float4 row chunks (nontemporal).

typedef float nfloat4 __attribute__((ext_vector_type(4)));

#define K1_CB 23   // classes per block chunk in table kernel
#define TC   64    // columns per block in main kernel

__global__ __launch_bounds__(256) void table_kernel(
    const float* __restrict__ logits,   // [N, C]
    const float* __restrict__ objs,     // [N, 1]
    float* __restrict__ tableT,         // [C, N]
    int N, int C)
{
    int n = blockIdx.x * 256 + threadIdx.x;
    if (n >= N) return;
    float po = __builtin_amdgcn_rcpf(1.0f + expf(-objs[n]));  // obj sigmoid
    int c0 = blockIdx.y * K1_CB;
    int c1 = c0 + K1_CB; if (c1 > C) c1 = C;
    for (int c = c0; c < c1; ++c) {
        float lg = logits[n * C + c];
        float ps = __builtin_amdgcn_rcpf(1.0f + expf(-lg));
        float p = ps * po;
        float omp = 1.0f - p;
        float pos = 0.25f * (omp * omp) * (-logf(p + 1e-8f));
        float neg = 0.75f * (p * p) * (-logf(omp + 1e-8f));
        tableT[(size_t)c * N + n] = pos - neg;   // coalesced write
    }
}

__global__ __launch_bounds__(256) void matcher_main(
    const float* __restrict__ boxes,    // [N, 4] cxcywh
    const float* __restrict__ points,   // [N, 2]
    const int*   __restrict__ labels,   // [T]
    const float* __restrict__ tboxes,   // [T, 4] cxcywh
    const float* __restrict__ tableT,   // [C, N]
    float* __restrict__ out,            // [N, T]
    int N, int T)
{
    __shared__ float4 s_box[TC];   // target xyxy
    __shared__ float2 s_al[TC];    // target area, label (as float bits)

    const int tid = threadIdx.x;
    const int tBase = blockIdx.x * TC;

    // ---- stage this block's TC targets (uniform data) ----
    if (tid < TC) {
        int t = tBase + tid;
        float4 tb = *(const float4*)(tboxes + 4 * t);
        float x0 = tb.x - 0.5f * tb.z;
        float y0 = tb.y - 0.5f * tb.w;
        float x1 = tb.x + 0.5f * tb.z;
        float y1 = tb.y + 0.5f * tb.w;
        s_box[tid] = make_float4(x0, y0, x1, y1);
        s_al[tid] = make_float2((x1 - x0) * (y1 - y0),
                                __int_as_float(labels[t]));
    }

    // ---- per-lane row constants (coalesced loads) ----
    const int n = blockIdx.y * 256 + tid;
    const bool valid = (n < N);
    const int nc = valid ? n : (N - 1);
    float4 b = *(const float4*)(boxes + 4 * nc);
    float x0 = b.x - 0.5f * b.z;
    float y0 = b.y - 0.5f * b.w;
    float x1 = b.x + 0.5f * b.z;
    float y1 = b.y + 0.5f * b.w;
    float a1 = (x1 - x0) * (y1 - y0);
    float2 pp = *(const float2*)(points + 2 * nc);
    float px = pp.x, py = pp.y;

    __syncthreads();

    float* orow = out + (size_t)nc * T + tBase;
    for (int tt = 0; tt < TC; tt += 4) {
        nfloat4 res;
        #pragma unroll
        for (int j = 0; j < 4; ++j) {
            int ti = tt + j;
            float4 tb = s_box[ti];        // LDS broadcast (same addr all lanes)
            float2 al = s_al[ti];
            float tx0 = tb.x, ty0 = tb.y, tx1 = tb.z, ty1 = tb.w;
            float tarea = al.x;
            int lab = __float_as_int(al.y);
            // coalesced per-lane read: 64 consecutive floats of tableT row
            float cc = tableT[(size_t)lab * N + nc];

            // L1 on xyxy
            float l1 = fabsf(x0 - tx0) + fabsf(y0 - ty0)
                     + fabsf(x1 - tx1) + fabsf(y1 - ty1);

            // intersection / union
            float iw = fminf(x1, tx1) - fmaxf(x0, tx0);
            float ih = fminf(y1, ty1) - fmaxf(y0, ty0);
            float inter = fmaxf(iw, 0.0f) * fmaxf(ih, 0.0f);
            float uni = (a1 + tarea) - inter;

            // enclosing box (extents >= 0 since w,h >= 0)
            float cw = fmaxf(x1, tx1) - fminf(x0, tx0);
            float ch = fmaxf(y1, ty1) - fminf(y0, ty0);
            float carea = cw * ch;

            // giou with a single rcp: R = 1/(uni*carea)
            float R = __builtin_amdgcn_rcpf(uni * carea);
            float giou = (inter * carea - uni * (carea - uni)) * R;

            // inner-point: exact reference op sequence (sign-exact)
            float left = px - tx0;
            float top = py - ty0;
            float right = tx1 - px;
            float bottom = ty1 - py;
            float mind = fminf(fminf(left, top), fminf(right, bottom));

            float Cv = fmaf(5.0f, l1, fmaf(2.0f, cc, -2.0f * giou));
            Cv += (mind >= 0.0f) ? 0.0f : 9999.0f;
            res[j] = Cv;
        }
        if (valid) {
            // write-once stream: nontemporal keeps L2 for the table
            __builtin_nontemporal_store(res, (nfloat4*)(orow + tt));
        }
    }
}

extern "C" void kernel_launch(void* const* d_in, const int* in_sizes, int n_in,
                              void* d_out, int out_size, void* d_ws, size_t ws_size,
                              hipStream_t stream) {
    const float* logits = (const float*)d_in[0];  // [bs,nq,nc]
    const float* boxes  = (const float*)d_in[1];  // [bs,nq,4]
    const float* points = (const float*)d_in[2];  // [bs,nq,2]
    const float* objs   = (const float*)d_in[3];  // [bs,nq,1]
    const int*   labels = (const int*)d_in[4];    // [T]
    const float* tboxes = (const float*)d_in[5];  // [T,4]
    float* out = (float*)d_out;
    float* tableT = (float*)d_ws;                 // [C, N] = 5.2 MB

    int N = in_sizes[1] / 4;        // 14400
    int T = in_sizes[5] / 4;        // 1024
    int C = in_sizes[0] / N;        // 91

    dim3 g1((N + 255) / 256, (C + K1_CB - 1) / K1_CB);
    table_kernel<<<g1, 256, 0, stream>>>(logits, objs, tableT, N, C);

    dim3 g2(T / TC, (N + 255) / 256);
    matcher_main<<<g2, 256, 0, stream>>>(boxes, points, labels, tboxes,
                                         tableT, out, N, T);
}

// Round 7
// 119.233 us; speedup vs baseline: 2.0202x; 2.0202x over previous
//
#include <hip/hip_runtime.h>
#include <math.h>

// Hungarian matcher cost matrix:
//   C[n,t] = 5*L1(xyxy) + 2*(focal@label[t]) - 2*GIoU + 9999*inner
// N = 14400, T = 1024, C = 91. Output [N,T] f32 (59 MB).
//
// R7: R1-R4 (lane<->column, coalesced stores) all stuck at 45-53us kernel
// with every pipe <35% busy. R6 (lane<->row) proved scattered stores are
// fatal (WRITE_SIZE 2.4x). This round keeps coalesced stores and removes
// ALL remaining structural invariants of the 45us wall:
//   - no LDS, no __syncthreads in the hot kernel
//   - focal table precomputed ROW-MAJOR table[n][96] (per-wave gather span
//     = 91 words ~ 6 L2 lines, not a page scatter)
//   - per-row constants packed + block-uniform -> scalar (SGPR) loads
//   - per-target constants packed -> 2 coalesced dwordx4 per t
//   - 32 independent L2 gathers prefetched, then pure math, then 8
//     back-to-back 1KB/wave stores.

#define TSTR 96      // table row stride (>= 91, 16B multiple)

// ws layout (bytes):
//   table   @ 0        : N*TSTR*4   = 5,529,600
//   rowpack @ 0x580000 : N*8*4      =   460,800  (x0,y0,x1,y1,px,py,a1,pad)
//   tgtpack @ 0x600000 : T*8*4      =    32,768  (tx0,ty0,tx1,ty1,tarea,labf,0,0)
#define ROWPACK_OFF 0x580000
#define TGTPACK_OFF 0x600000

__global__ __launch_bounds__(256) void prep_kernel(
    const float* __restrict__ logits,   // [N, C]
    const float* __restrict__ boxes,    // [N, 4] cxcywh
    const float* __restrict__ points,   // [N, 2]
    const float* __restrict__ objs,     // [N, 1]
    const int*   __restrict__ labels,   // [T]
    const float* __restrict__ tboxes,   // [T, 4] cxcywh
    float* __restrict__ ws,
    int N, int C, int T)
{
    float* table   = ws;
    float* rowpack = (float*)((char*)ws + ROWPACK_OFF);
    float* tgtpack = (float*)((char*)ws + TGTPACK_OFF);

    const int n  = blockIdx.x * 256 + threadIdx.x;
    const int cy = blockIdx.y;

    if (cy == 7) {
        // pack per-row pred constants
        if (n < N) {
            float4 b = *(const float4*)(boxes + 4 * n);
            float x0 = b.x - 0.5f * b.z;
            float y0 = b.y - 0.5f * b.w;
            float x1 = b.x + 0.5f * b.z;
            float y1 = b.y + 0.5f * b.w;
            float2 p = *(const float2*)(points + 2 * n);
            float* rp = rowpack + 8 * n;
            rp[0] = x0; rp[1] = y0; rp[2] = x1; rp[3] = y1;
            rp[4] = p.x; rp[5] = p.y; rp[6] = (x1 - x0) * (y1 - y0); rp[7] = 0.f;
        }
        // pack per-target constants (first T global threads of this slice)
        if (n < T) {
            float4 tb = *(const float4*)(tboxes + 4 * n);
            float x0 = tb.x - 0.5f * tb.z;
            float y0 = tb.y - 0.5f * tb.w;
            float x1 = tb.x + 0.5f * tb.z;
            float y1 = tb.y + 0.5f * tb.w;
            float* tp = tgtpack + 8 * n;
            tp[0] = x0; tp[1] = y0; tp[2] = x1; tp[3] = y1;
            tp[4] = (x1 - x0) * (y1 - y0);
            tp[5] = __int_as_float(labels[n]);
            tp[6] = 0.f; tp[7] = 0.f;
        }
        return;
    }

    // focal class-cost table chunk: 13 classes per y-slice (7*13 = 91)
    if (n >= N) return;
    float po = __builtin_amdgcn_rcpf(1.0f + expf(-objs[n]));  // obj sigmoid
    int c0 = cy * 13;
    int c1 = c0 + 13; if (c1 > C) c1 = C;
    float* trow = table + (size_t)n * TSTR;
    for (int c = c0; c < c1; ++c) {
        float lg = logits[n * C + c];
        float ps = __builtin_amdgcn_rcpf(1.0f + expf(-lg));
        float p = ps * po;
        float omp = 1.0f - p;
        float pos = 0.25f * (omp * omp) * (-logf(p + 1e-8f));
        float neg = 0.75f * (p * p) * (-logf(omp + 1e-8f));
        trow[c] = pos - neg;
    }
}

// main: block = 8 rows x 1024 columns, 256 threads x VT=4 columns.
// grid = N/8 = 1800. No LDS, no barrier.
#define BN 8
#define VT 4

__global__ __launch_bounds__(256) void matcher_main(
    const float* __restrict__ ws_ro,
    float* __restrict__ out,            // [N, T]
    int N, int T)
{
    const float* table   = ws_ro;
    const float* rowpack = (const float*)((const char*)ws_ro + ROWPACK_OFF);
    const float* tgtpack = (const float*)((const char*)ws_ro + TGTPACK_OFF);

    const int tid = threadIdx.x;
    const int rowBase = blockIdx.x * BN;
    const int t0 = tid * VT;

    // ---- per-target constants: 2 coalesced dwordx4 per column ----
    float tx0[VT], ty0[VT], tx1[VT], ty1[VT], tarea[VT];
    int lab[VT];
    #pragma unroll
    for (int j = 0; j < VT; ++j) {
        const float4* tp = (const float4*)(tgtpack + 8 * (t0 + j));
        float4 a = tp[0];
        float4 b = tp[1];
        tx0[j] = a.x; ty0[j] = a.y; tx1[j] = a.z; ty1[j] = a.w;
        tarea[j] = b.x;
        lab[j] = __float_as_int(b.y);
    }

    // ---- class-cost gathers: 32 independent L2 loads (91-word span/row) ----
    float cc[BN][VT];
    #pragma unroll
    for (int r = 0; r < BN; ++r) {
        const float* trow = table + (size_t)(rowBase + r) * TSTR;
        #pragma unroll
        for (int j = 0; j < VT; ++j)
            cc[r][j] = trow[lab[j]];
    }

    // ---- per-row constants: block-uniform -> scalar loads ----
    // (address depends only on blockIdx -> compiler emits s_load)
    const float* rp = rowpack + (size_t)rowBase * 8;

    float* obase = out + (size_t)rowBase * T + t0;
    #pragma unroll
    for (int r = 0; r < BN; ++r) {
        float x0 = rp[r * 8 + 0], y0 = rp[r * 8 + 1];
        float x1 = rp[r * 8 + 2], y1 = rp[r * 8 + 3];
        float px = rp[r * 8 + 4], py = rp[r * 8 + 5];
        float a1 = rp[r * 8 + 6];

        float4 res;
        float* resp = (float*)&res;
        #pragma unroll
        for (int j = 0; j < VT; ++j) {
            // L1 on xyxy
            float l1 = fabsf(x0 - tx0[j]) + fabsf(y0 - ty0[j])
                     + fabsf(x1 - tx1[j]) + fabsf(y1 - ty1[j]);

            // intersection / union
            float iw = fminf(x1, tx1[j]) - fmaxf(x0, tx0[j]);
            float ih = fminf(y1, ty1[j]) - fmaxf(y0, ty0[j]);
            float inter = fmaxf(iw, 0.0f) * fmaxf(ih, 0.0f);
            float uni = (a1 + tarea[j]) - inter;

            // enclosing box (extents >= 0 since w,h >= 0)
            float cw = fmaxf(x1, tx1[j]) - fminf(x0, tx0[j]);
            float ch = fmaxf(y1, ty1[j]) - fminf(y0, ty0[j]);
            float carea = cw * ch;

            // giou with a single rcp: R = 1/(uni*carea)
            float R = __builtin_amdgcn_rcpf(uni * carea);
            float giou = (inter * carea - uni * (carea - uni)) * R;

            // inner-point: exact reference op sequence (sign-exact)
            float left = px - tx0[j];
            float top = py - ty0[j];
            float right = tx1[j] - px;
            float bottom = ty1[j] - py;
            float mind = fminf(fminf(left, top), fminf(right, bottom));

            float Cv = fmaf(5.0f, l1, fmaf(2.0f, cc[r][j], -2.0f * giou));
            Cv += (mind >= 0.0f) ? 0.0f : 9999.0f;
            resp[j] = Cv;
        }
        *(float4*)(obase + (size_t)r * T) = res;   // 1KB/wave coalesced
    }
}

extern "C" void kernel_launch(void* const* d_in, const int* in_sizes, int n_in,
                              void* d_out, int out_size, void* d_ws, size_t ws_size,
                              hipStream_t stream) {
    const float* logits = (const float*)d_in[0];  // [bs,nq,nc]
    const float* boxes  = (const float*)d_in[1];  // [bs,nq,4]
    const float* points = (const float*)d_in[2];  // [bs,nq,2]
    const float* objs   = (const float*)d_in[3];  // [bs,nq,1]
    const int*   labels = (const int*)d_in[4];    // [T]
    const float* tboxes = (const float*)d_in[5];  // [T,4]
    float* out = (float*)d_out;
    float* ws = (float*)d_ws;

    int N = in_sizes[1] / 4;        // 14400
    int T = in_sizes[5] / 4;        // 1024
    int C = in_sizes[0] / N;        // 91

    dim3 gp((N + 255) / 256, 8);    // y=0..6: table chunks; y=7: packs
    prep_kernel<<<gp, 256, 0, stream>>>(logits, boxes, points, objs,
                                        labels, tboxes, ws, N, C, T);

    matcher_main<<<dim3(N / BN), 256, 0, stream>>>(ws, out, N, T);
}

// Round 8
// 97.690 us; speedup vs baseline: 2.4657x; 1.2205x over previous
//
#include <hip/hip_runtime.h>
#include <math.h>

// Hungarian matcher cost matrix:
//   C[n,t] = 5*L1(xyxy) + 2*(focal@label[t]) - 2*GIoU + 9999*inner
// N = 14400, T = 1024, C = 91. Output [N,T] f32 (59 MB).
//
// R8: back to the best structure (R3/R4 fused, BN=8, 1800 blocks) with the
// three remaining hot-path cuts:
//  - fast __expf/__logf (v_exp_f32/v_log_f32) in the focal table: 9 libm
//    calls/thread (~30 instr each) -> 9 single-instr transcendentals.
//    Threshold is 200.96 absolute; ~1e-5 relative error is irrelevant.
//  - LDS table TRANSPOSED to [class][8 rows] (stride 8 floats = 32 B,
//    16B-aligned): per-thread class gather becomes 8x ds_read_b128 instead
//    of 32x conflicted ds_read_b32.
//  - rcp for obj-sigmoid denominator.
// Inner-point term keeps the exact reference op sequence (sign-exact).

#define BN 8
#define BT 256
#define VT 4

__global__ __launch_bounds__(BT) void matcher_kernel(
    const float* __restrict__ logits,   // [N, C]
    const float* __restrict__ boxes,    // [N, 4] cxcywh
    const float* __restrict__ points,   // [N, 2]
    const float* __restrict__ objs,     // [N, 1]
    const int*   __restrict__ labels,   // [T]
    const float* __restrict__ tboxes,   // [T, 4] cxcywh
    float* __restrict__ out,            // [N, T]
    int N, int C, int T)
{
    __shared__ float s_tab[96 * BN];   // TRANSPOSED: s_tab[c*8 + r]
    __shared__ float s_row[BN][8];     // x0,y0,x1,y1 | px,py,area1,po

    const int tid = threadIdx.x;
    const int rowBase = blockIdx.y * BN;
    const int t0 = tid * VT;

    // ---- Phase 1a: per-row constants ----
    if (tid < BN) {
        int n = rowBase + tid;
        float4 b = *(const float4*)(boxes + 4 * n);
        float x0 = b.x - 0.5f * b.z;
        float y0 = b.y - 0.5f * b.w;
        float x1 = b.x + 0.5f * b.z;
        float y1 = b.y + 0.5f * b.w;
        s_row[tid][0] = x0;
        s_row[tid][1] = y0;
        s_row[tid][2] = x1;
        s_row[tid][3] = y1;
        float2 p = *(const float2*)(points + 2 * n);
        s_row[tid][4] = p.x;
        s_row[tid][5] = p.y;
        s_row[tid][6] = (x1 - x0) * (y1 - y0);
        s_row[tid][7] = __builtin_amdgcn_rcpf(1.0f + __expf(-objs[n]));
    }
    __syncthreads();

    // ---- Phase 1b: focal table, transposed write s_tab[c*8+r] ----
    // logits index = rowBase*C + idx (consecutive tid -> coalesced)
    for (int idx = tid; idx < BN * C; idx += BT) {
        int r = idx / C;
        int c = idx - r * C;
        float lg = logits[(size_t)rowBase * C + idx];
        float ps = __builtin_amdgcn_rcpf(1.0f + __expf(-lg));
        float p = ps * s_row[r][7];
        float omp = 1.0f - p;
        float pos = 0.25f * (omp * omp) * (-__logf(p + 1e-8f));
        float neg = 0.75f * (p * p) * (-__logf(omp + 1e-8f));
        s_tab[c * BN + r] = pos - neg;
    }
    __syncthreads();

    // ---- Phase 2: 4 target columns x 8 rows per thread ----
    {
        // target constants (coalesced global loads)
        int4 lv = *(const int4*)(labels + t0);
        int lab[VT] = {lv.x, lv.y, lv.z, lv.w};
        float tx0[VT], ty0[VT], tx1[VT], ty1[VT], tarea[VT];
        #pragma unroll
        for (int j = 0; j < VT; ++j) {
            float4 tb = *(const float4*)(tboxes + 4 * (t0 + j));
            tx0[j] = tb.x - 0.5f * tb.z;
            ty0[j] = tb.y - 0.5f * tb.w;
            tx1[j] = tb.x + 0.5f * tb.z;
            ty1[j] = tb.y + 0.5f * tb.w;
            tarea[j] = (tx1[j] - tx0[j]) * (ty1[j] - ty0[j]);
        }

        // class costs: per j, all 8 rows in 2 ds_read_b128 (16B-aligned)
        float cc[VT][BN];
        #pragma unroll
        for (int j = 0; j < VT; ++j) {
            const float4* tp = (const float4*)(s_tab + lab[j] * BN);
            float4 lo = tp[0];
            float4 hi = tp[1];
            cc[j][0] = lo.x; cc[j][1] = lo.y; cc[j][2] = lo.z; cc[j][3] = lo.w;
            cc[j][4] = hi.x; cc[j][5] = hi.y; cc[j][6] = hi.z; cc[j][7] = hi.w;
        }

        // row constants -> registers (broadcast b128 reads)
        float rx0[BN], ry0[BN], rx1[BN], ry1[BN], rpx[BN], rpy[BN], ra1[BN];
        #pragma unroll
        for (int r = 0; r < BN; ++r) {
            float4 ra = *(const float4*)&s_row[r][0];
            float4 rb = *(const float4*)&s_row[r][4];
            rx0[r] = ra.x; ry0[r] = ra.y; rx1[r] = ra.z; ry1[r] = ra.w;
            rpx[r] = rb.x; rpy[r] = rb.y; ra1[r] = rb.z;
        }

        float* obase = out + (size_t)rowBase * T + t0;
        #pragma unroll
        for (int r = 0; r < BN; ++r) {
            float x0 = rx0[r], y0 = ry0[r], x1 = rx1[r], y1 = ry1[r];
            float px = rpx[r], py = rpy[r], a1 = ra1[r];

            float4 res;
            float* resp = (float*)&res;
            #pragma unroll
            for (int j = 0; j < VT; ++j) {
                // L1 on xyxy
                float l1 = fabsf(x0 - tx0[j]) + fabsf(y0 - ty0[j])
                         + fabsf(x1 - tx1[j]) + fabsf(y1 - ty1[j]);

                // intersection / union
                float iw = fminf(x1, tx1[j]) - fmaxf(x0, tx0[j]);
                float ih = fminf(y1, ty1[j]) - fmaxf(y0, ty0[j]);
                float inter = fmaxf(iw, 0.0f) * fmaxf(ih, 0.0f);
                float uni = (a1 + tarea[j]) - inter;

                // enclosing box (extents >= 0 since w,h >= 0)
                float cw = fmaxf(x1, tx1[j]) - fminf(x0, tx0[j]);
                float ch = fmaxf(y1, ty1[j]) - fminf(y0, ty0[j]);
                float carea = cw * ch;

                // giou with a single rcp: R = 1/(uni*carea)
                float R = __builtin_amdgcn_rcpf(uni * carea);
                float giou = (inter * carea - uni * (carea - uni)) * R;

                // inner-point: exact reference op sequence (sign-exact)
                float left = px - tx0[j];
                float top = py - ty0[j];
                float right = tx1[j] - px;
                float bottom = ty1[j] - py;
                float mind = fminf(fminf(left, top), fminf(right, bottom));

                float Cv = fmaf(5.0f, l1, fmaf(2.0f, cc[j][r], -2.0f * giou));
                Cv += (mind >= 0.0f) ? 0.0f : 9999.0f;
                resp[j] = Cv;
            }
            *(float4*)(obase + (size_t)r * T) = res;   // 1KB/wave coalesced
        }
    }
}

extern "C" void kernel_launch(void* const* d_in, const int* in_sizes, int n_in,
                              void* d_out, int out_size, void* d_ws, size_t ws_size,
                              hipStream_t stream) {
    const float* logits = (const float*)d_in[0];  // [bs,nq,nc]
    const float* boxes  = (const float*)d_in[1];  // [bs,nq,4]
    const float* points = (const float*)d_in[2];  // [bs,nq,2]
    const float* objs   = (const float*)d_in[3];  // [bs,nq,1]
    const int*   labels = (const int*)d_in[4];    // [T]
    const float* tboxes = (const float*)d_in[5];  // [T,4]
    float* out = (float*)d_out;

    int N = in_sizes[1] / 4;        // 14400
    int T = in_sizes[5] / 4;        // 1024
    int C = in_sizes[0] / N;        // 91

    dim3 grid(1, N / BN);           // 1800 blocks; each covers 8 rows x 1024 cols
    matcher_kernel<<<grid, BT, 0, stream>>>(logits, boxes, points, objs,
                                            labels, tboxes, out, N, C, T);
}